// Round 2
// baseline (56.058 us; speedup 1.0000x reference)
//
#include <hip/hip_runtime.h>
#include <hip/hip_bf16.h>

constexpr int L_LEN = 4096;
constexpr int CH = 8;          // channels
constexpr int S_SAMPLES = 256; // continuous start samples
constexpr int K_SAMP = 32;     // shapelet samples
constexpr int NSHAPE = 16;
constexpr int NB = 32;         // batch
constexpr int THREADS = 256;   // = 4 quarters x 32 b x 2 p

// tid bits: [0:1] = quarter (k-range), [2:6] = b, [7] = p_local
__global__ __launch_bounds__(THREADS, 4) void shapelet_min_kernel(
    const float* __restrict__ path,      // (B, L, C)
    const float* __restrict__ lengths,   // (NSHAPE)
    const float* __restrict__ shapelets, // (NSHAPE, K, C)
    unsigned int* __restrict__ ws_min)   // (NSHAPE, NB) float-as-uint
{
    __shared__ float sh[K_SAMP * CH];    // 1 KB, this block's shapelet
    __shared__ float red[2][NB];

    const int s       = blockIdx.y;
    const int tid     = threadIdx.x;
    const int quarter = tid & 3;
    const int b       = (tid >> 2) & (NB - 1);
    const int pl      = tid >> 7;                 // 0..1
    const int p       = blockIdx.x * 2 + pl;      // 0..255

    for (int i = tid; i < K_SAMP * CH; i += THREADS)
        sh[i] = shapelets[s * K_SAMP * CH + i];
    __syncthreads();

    const float len  = fminf(fmaxf(lengths[s], 0.01f), 512.0f);
    const float tN   = (float)(L_LEN - 1);
    const float start = ((float)p / (float)(S_SAMPLES - 1)) * (tN - len);
    const float step  = len * (1.0f / (float)(K_SAMP - 1));

    const int k0 = quarter * 8;

    const float4* __restrict__ prow =
        reinterpret_cast<const float4*>(path) + (size_t)b * (L_LEN * (CH / 4));

    float dprev[CH];
    float sqprev = 0.f;
    float segsum = 0.f;

    // sample i = 0 (k = k0)
    {
        const float q = start + (float)k0 * step;
        int idx = (int)floorf(q);
        idx = min(max(idx, 0), L_LEN - 2);
        const float r = q - (float)idx;
        const float4 a0 = prow[idx * 2 + 0];
        const float4 a1 = prow[idx * 2 + 1];
        const float4 c0 = prow[idx * 2 + 2];
        const float4 c1 = prow[idx * 2 + 3];
        const float pv[CH] = {a0.x, a0.y, a0.z, a0.w, a1.x, a1.y, a1.z, a1.w};
        const float nv[CH] = {c0.x, c0.y, c0.z, c0.w, c1.x, c1.y, c1.z, c1.w};
        float sq = 0.f;
        #pragma unroll
        for (int c = 0; c < CH; ++c) {
            const float samp = pv[c] + r * (nv[c] - pv[c]);
            const float d = samp - sh[k0 * CH + c];
            dprev[c] = d;
            sq += d * d;
        }
        sqprev = sq;
    }

    // segments i = 1..8 (sample k = k0+i), last one of quarter 3 weighted 0
    #pragma unroll
    for (int i = 1; i <= 8; ++i) {
        const int k  = k0 + i;
        const int kk = min(k, K_SAMP - 1);
        const float w = (k <= K_SAMP - 1) ? 1.0f : 0.0f;

        const float q = start + (float)kk * step;
        int idx = (int)floorf(q);
        idx = min(max(idx, 0), L_LEN - 2);
        const float r = q - (float)idx;
        const float4 a0 = prow[idx * 2 + 0];
        const float4 a1 = prow[idx * 2 + 1];
        const float4 c0 = prow[idx * 2 + 2];
        const float4 c1 = prow[idx * 2 + 3];
        const float pv[CH] = {a0.x, a0.y, a0.z, a0.w, a1.x, a1.y, a1.z, a1.w};
        const float nv[CH] = {c0.x, c0.y, c0.z, c0.w, c1.x, c1.y, c1.z, c1.w};

        float sq = 0.f, dot = 0.f;
        float d[CH];
        #pragma unroll
        for (int c = 0; c < CH; ++c) {
            const float samp = pv[c] + r * (nv[c] - pv[c]);
            d[c] = samp - sh[kk * CH + c];
            sq  += d[c] * d[c];
            dot += dprev[c] * d[c];
        }
        segsum += w * (sqprev + dot + sq);
        sqprev = sq;
        #pragma unroll
        for (int c = 0; c < CH; ++c) dprev[c] = d[c];
    }

    // reduce the 4 quarters (adjacent lanes 0..3 within the wave)
    segsum += __shfl_xor(segsum, 1);
    segsum += __shfl_xor(segsum, 2);

    // integral = dt/3 * segsum, dt = len/(K-1)
    float integral = len * (1.0f / (3.0f * (float)(K_SAMP - 1))) * segsum;
    integral = fmaxf(integral, 0.0f); // keep uint-min ordering valid

    if (quarter == 0) red[pl][b] = integral;
    __syncthreads();
    if (tid < NB) {
        const float m = fminf(red[0][tid], red[1][tid]);
        atomicMin(ws_min + s * NB + tid, __float_as_uint(m));
    }
}

__global__ void shapelet_finalize_kernel(const unsigned int* __restrict__ ws_min,
                                         float* __restrict__ out)
{
    const int i = threadIdx.x + blockIdx.x * blockDim.x;
    if (i < NSHAPE * NB) {
        const int s = i / NB;
        const int b = i % NB;
        const float v = __uint_as_float(ws_min[i]);
        out[b * NSHAPE + s] = sqrtf(fmaxf(v, 1e-12f));
    }
}

extern "C" void kernel_launch(void* const* d_in, const int* in_sizes, int n_in,
                              void* d_out, int out_size, void* d_ws, size_t ws_size,
                              hipStream_t stream) {
    // inputs: times (L), path (B,L,C), lengths (NSHAPE), shapelets (NSHAPE,K,C)
    const float* path      = (const float*)d_in[1];
    const float* lengths   = (const float*)d_in[2];
    const float* shapelets = (const float*)d_in[3];
    float* out = (float*)d_out;
    unsigned int* ws_min = (unsigned int*)d_ws;

    // init mins to huge float (0x7f7f7f7f ~ 3.39e38), deterministic each call
    hipMemsetAsync(ws_min, 0x7f, NSHAPE * NB * sizeof(unsigned int), stream);

    dim3 grid(S_SAMPLES / 2, NSHAPE);
    shapelet_min_kernel<<<grid, THREADS, 0, stream>>>(path, lengths, shapelets, ws_min);
    shapelet_finalize_kernel<<<1, NSHAPE * NB, 0, stream>>>(ws_min, out);
}

// Round 3
// 39.368 us; speedup vs baseline: 1.4240x; 1.4240x over previous
//
#include <hip/hip_runtime.h>
#include <hip/hip_bf16.h>

constexpr int L_LEN = 4096;
constexpr int CH = 8;          // channels
constexpr int S_SAMPLES = 256; // continuous start samples
constexpr int K_SAMP = 32;     // shapelet samples
constexpr int NSHAPE = 16;
constexpr int NB = 32;         // batch
constexpr int NPB = 4;                  // p values per block
constexpr int NPBLK = S_SAMPLES / NPB;  // 64 p-blocks
constexpr int THREADS = 256;            // b(32) x half(2) x pl(4)

// path (B,L,C) -> ws (L,B,C); write-coalesced, reads scatter (one-time 4MB)
__global__ __launch_bounds__(256) void transpose_kernel(const float4* __restrict__ src,
                                                        float4* __restrict__ dst) {
    const int t  = blockIdx.x * 256 + threadIdx.x;  // 262144 float4s
    const int c4 = t & 1;
    const int b  = (t >> 1) & (NB - 1);
    const int l  = t >> 6;
    dst[t] = src[(b * L_LEN + l) * 2 + c4];
}

// tid bits: [0:4]=b, [5]=half (k-split), [6:7]=pl
__global__ __launch_bounds__(THREADS) void shapelet_min_kernel(
    const float* __restrict__ wst,       // (L, B, C) transposed path
    const float* __restrict__ lengths,   // (NSHAPE)
    const float* __restrict__ shapelets, // (NSHAPE, K, C)
    float* __restrict__ partial)         // (NSHAPE, NPBLK, NB)
{
    __shared__ float sh[K_SAMP][CH + 1]; // +1 pad: stride 9 floats -> conflict-free
    __shared__ float red[NPB][NB];

    const int s    = blockIdx.y;
    const int tid  = threadIdx.x;
    const int b    = tid & (NB - 1);
    const int half = (tid >> 5) & 1;
    const int pl   = tid >> 6;                    // 0..3
    const int p    = blockIdx.x * NPB + pl;       // 0..255

    if (tid < K_SAMP * CH) sh[tid >> 3][tid & 7] = shapelets[s * K_SAMP * CH + tid];
    __syncthreads();

    const float len   = fminf(fmaxf(lengths[s], 0.01f), 512.0f);
    const float start = ((float)p / (float)(S_SAMPLES - 1)) * ((float)(L_LEN - 1) - len);
    const float step  = len * (1.0f / (float)(K_SAMP - 1));
    const int   k0    = half * (K_SAMP / 2);      // 0 or 16

    const float4* __restrict__ w4 = reinterpret_cast<const float4*>(wst);

    float dprev[CH];
    float sqprev = 0.f, segsum = 0.f;

    // sample i = 0 (k = k0); q >= 0 so (int)q == floor(q)
    {
        const float q = start + (float)k0 * step;
        const int idx = min(max((int)q, 0), L_LEN - 2);
        const float r = q - (float)idx;
        const int base = (idx * NB + b) * 2;
        const float4 a0 = w4[base + 0];
        const float4 a1 = w4[base + 1];
        const float4 c0 = w4[base + 2 * NB + 0];
        const float4 c1 = w4[base + 2 * NB + 1];
        const float pv[CH] = {a0.x, a0.y, a0.z, a0.w, a1.x, a1.y, a1.z, a1.w};
        const float nv[CH] = {c0.x, c0.y, c0.z, c0.w, c1.x, c1.y, c1.z, c1.w};
        float sq = 0.f;
        #pragma unroll
        for (int c = 0; c < CH; ++c) {
            const float samp = pv[c] + r * (nv[c] - pv[c]);
            const float d = samp - sh[k0][c];
            dprev[c] = d;
            sq += d * d;
        }
        sqprev = sq;
    }

    // segments i = 1..16 (sample k = k0+i); half 1's i=16 is weighted 0
    #pragma unroll 4
    for (int i = 1; i <= K_SAMP / 2; ++i) {
        const int k  = k0 + i;
        const int kk = min(k, K_SAMP - 1);
        const float w = (k <= K_SAMP - 1) ? 1.0f : 0.0f;

        const float q = start + (float)kk * step;
        const int idx = min(max((int)q, 0), L_LEN - 2);
        const float r = q - (float)idx;
        const int base = (idx * NB + b) * 2;
        const float4 a0 = w4[base + 0];
        const float4 a1 = w4[base + 1];
        const float4 c0 = w4[base + 2 * NB + 0];
        const float4 c1 = w4[base + 2 * NB + 1];
        const float pv[CH] = {a0.x, a0.y, a0.z, a0.w, a1.x, a1.y, a1.z, a1.w};
        const float nv[CH] = {c0.x, c0.y, c0.z, c0.w, c1.x, c1.y, c1.z, c1.w};

        float sq = 0.f, dot = 0.f;
        float d[CH];
        #pragma unroll
        for (int c = 0; c < CH; ++c) {
            const float samp = pv[c] + r * (nv[c] - pv[c]);
            d[c] = samp - sh[kk][c];
            sq  += d[c] * d[c];
            dot += dprev[c] * d[c];
        }
        segsum += w * (sqprev + dot + sq);
        sqprev = sq;
        #pragma unroll
        for (int c = 0; c < CH; ++c) dprev[c] = d[c];
    }

    // combine the two halves (lane ^ 32, same wave)
    segsum += __shfl_xor(segsum, 32);

    float integral = len * (1.0f / (3.0f * (float)(K_SAMP - 1))) * segsum;
    integral = fmaxf(integral, 0.0f);

    if (half == 0) red[pl][b] = integral;
    __syncthreads();
    if (tid < NB) {
        float m = red[0][tid];
        #pragma unroll
        for (int j = 1; j < NPB; ++j) m = fminf(m, red[j][tid]);
        partial[(s * NPBLK + blockIdx.x) * NB + tid] = m;
    }
}

__global__ __launch_bounds__(NSHAPE * NB) void shapelet_finalize_kernel(
    const float* __restrict__ partial, float* __restrict__ out)
{
    const int t = threadIdx.x;            // 512
    const int s = t >> 5;
    const int b = t & (NB - 1);
    float m = 3.4e38f;
    for (int pb = 0; pb < NPBLK; ++pb)
        m = fminf(m, partial[(s * NPBLK + pb) * NB + b]);
    out[b * NSHAPE + s] = sqrtf(fmaxf(m, 1e-12f));
}

extern "C" void kernel_launch(void* const* d_in, const int* in_sizes, int n_in,
                              void* d_out, int out_size, void* d_ws, size_t ws_size,
                              hipStream_t stream) {
    // inputs: times (L), path (B,L,C), lengths (NSHAPE), shapelets (NSHAPE,K,C)
    const float* path      = (const float*)d_in[1];
    const float* lengths   = (const float*)d_in[2];
    const float* shapelets = (const float*)d_in[3];
    float* out = (float*)d_out;

    float* wst     = (float*)d_ws;                                   // 4 MB
    float* partial = (float*)((char*)d_ws + (size_t)L_LEN * NB * CH * 4); // 128 KB

    transpose_kernel<<<L_LEN * NB * CH / 4 / 256, 256, 0, stream>>>(
        (const float4*)path, (float4*)wst);
    dim3 grid(NPBLK, NSHAPE);
    shapelet_min_kernel<<<grid, THREADS, 0, stream>>>(wst, lengths, shapelets, partial);
    shapelet_finalize_kernel<<<1, NSHAPE * NB, 0, stream>>>(partial, out);
}

// Round 4
// 29.625 us; speedup vs baseline: 1.8922x; 1.3288x over previous
//
#include <hip/hip_runtime.h>
#include <hip/hip_bf16.h>

constexpr int L_LEN = 4096;
constexpr int CH = 8;          // channels
constexpr int S_SAMPLES = 256; // continuous start samples
constexpr int K_SAMP = 32;     // shapelet samples
constexpr int NSHAPE = 16;
constexpr int NB = 32;         // batch
constexpr int NPB = 2;                  // p values per block
constexpr int NPBLK = S_SAMPLES / NPB;  // 128 p-blocks
constexpr int THREADS = 256;            // b(32) x quarter(4) x pl(2)

// path (B,L,C) -> ws (L,B,C); write-coalesced, reads scatter (one-time 4MB)
__global__ __launch_bounds__(256) void transpose_kernel(const float4* __restrict__ src,
                                                        float4* __restrict__ dst) {
    const int t  = blockIdx.x * 256 + threadIdx.x;  // 262144 float4s
    const int c4 = t & 1;
    const int b  = (t >> 1) & (NB - 1);
    const int l  = t >> 6;
    dst[t] = src[(b * L_LEN + l) * 2 + c4];
}

// tid bits: [0:4]=b, [5]=q_lo, [6]=q_hi, [7]=pl  (quarter = bits 5:6)
__global__ __launch_bounds__(THREADS) void shapelet_min_kernel(
    const float* __restrict__ wst,       // (L, B, C) transposed path
    const float* __restrict__ lengths,   // (NSHAPE)
    const float* __restrict__ shapelets, // (NSHAPE, K, C)
    float* __restrict__ partial)         // (NSHAPE, NPBLK, NB)
{
    __shared__ float sh[K_SAMP][CH + 1]; // stride 9 floats -> conflict-free
    __shared__ float sred[NPB][2][NB];   // [pl][q_hi][b]

    const int s       = blockIdx.y;
    const int tid     = threadIdx.x;
    const int b       = tid & (NB - 1);
    const int quarter = (tid >> 5) & 3;
    const int q_hi    = (tid >> 6) & 1;
    const int pl      = tid >> 7;                  // 0..1
    const int p       = blockIdx.x * NPB + pl;     // 0..255

    sh[tid >> 3][tid & 7] = shapelets[s * K_SAMP * CH + tid];  // 256 == K*CH
    __syncthreads();

    const float len   = fminf(fmaxf(lengths[s], 0.01f), 512.0f);
    const float start = ((float)p / (float)(S_SAMPLES - 1)) * ((float)(L_LEN - 1) - len);
    const float step  = len * (1.0f / (float)(K_SAMP - 1));
    const int   k0    = quarter * (K_SAMP / 4);    // 0, 8, 16, 24

    const float4* __restrict__ w4 = reinterpret_cast<const float4*>(wst);

    float dprev[CH];
    float sqprev = 0.f, segsum = 0.f;

    // sample i = 0 (k = k0); q >= 0 so (int)q == floor(q)
    {
        const float q = start + (float)k0 * step;
        const int idx = min(max((int)q, 0), L_LEN - 2);
        const float r = q - (float)idx;
        const int base = (idx * NB + b) * 2;
        const float4 a0 = w4[base + 0];
        const float4 a1 = w4[base + 1];
        const float4 c0 = w4[base + 2 * NB + 0];
        const float4 c1 = w4[base + 2 * NB + 1];
        const float pv[CH] = {a0.x, a0.y, a0.z, a0.w, a1.x, a1.y, a1.z, a1.w};
        const float nv[CH] = {c0.x, c0.y, c0.z, c0.w, c1.x, c1.y, c1.z, c1.w};
        float sq = 0.f;
        #pragma unroll
        for (int c = 0; c < CH; ++c) {
            const float samp = pv[c] + r * (nv[c] - pv[c]);
            const float d = samp - sh[k0][c];
            dprev[c] = d;
            sq += d * d;
        }
        sqprev = sq;
    }

    // segments i = 1..8 (sample k = k0+i); quarter 3's i=8 (k=32) weighted 0
    #pragma unroll 4
    for (int i = 1; i <= K_SAMP / 4; ++i) {
        const int k  = k0 + i;
        const int kk = min(k, K_SAMP - 1);
        const float w = (k <= K_SAMP - 1) ? 1.0f : 0.0f;

        const float q = start + (float)kk * step;
        const int idx = min(max((int)q, 0), L_LEN - 2);
        const float r = q - (float)idx;
        const int base = (idx * NB + b) * 2;
        const float4 a0 = w4[base + 0];
        const float4 a1 = w4[base + 1];
        const float4 c0 = w4[base + 2 * NB + 0];
        const float4 c1 = w4[base + 2 * NB + 1];
        const float pv[CH] = {a0.x, a0.y, a0.z, a0.w, a1.x, a1.y, a1.z, a1.w};
        const float nv[CH] = {c0.x, c0.y, c0.z, c0.w, c1.x, c1.y, c1.z, c1.w};

        float sq = 0.f, dot = 0.f;
        float d[CH];
        #pragma unroll
        for (int c = 0; c < CH; ++c) {
            const float samp = pv[c] + r * (nv[c] - pv[c]);
            d[c] = samp - sh[kk][c];
            sq  += d[c] * d[c];
            dot += dprev[c] * d[c];
        }
        segsum += w * (sqprev + dot + sq);
        sqprev = sq;
        #pragma unroll
        for (int c = 0; c < CH; ++c) dprev[c] = d[c];
    }

    // combine quarter pairs (lane bit 5, same wave)
    segsum += __shfl_xor(segsum, 32);
    if ((tid & 32) == 0) sred[pl][q_hi][b] = segsum;
    __syncthreads();

    if (tid < 64) {
        const int bb  = tid & (NB - 1);
        const int plx = tid >> 5;
        const float tot = sred[plx][0][bb] + sred[plx][1][bb];
        float integral = len * (1.0f / (3.0f * (float)(K_SAMP - 1))) * tot;
        integral = fmaxf(integral, 0.0f);
        // min over the block's two p values (lane bit 5)
        const float m = fminf(integral, __shfl_xor(integral, 32));
        if (tid < NB)
            partial[(s * NPBLK + blockIdx.x) * NB + bb] = m;
    }
}

// one block per shapelet; 256 threads = b(32) x chunk(8)
__global__ __launch_bounds__(256) void shapelet_finalize_kernel(
    const float* __restrict__ partial, float* __restrict__ out)
{
    __shared__ float fred[8][NB];
    const int s     = blockIdx.x;
    const int tid   = threadIdx.x;
    const int b     = tid & (NB - 1);
    const int chunk = tid >> 5;                   // 0..7
    float m = 3.4e38f;
    #pragma unroll
    for (int j = 0; j < NPBLK / 8; ++j) {
        const int pb = chunk * (NPBLK / 8) + j;
        m = fminf(m, partial[(s * NPBLK + pb) * NB + b]);
    }
    fred[chunk][b] = m;
    __syncthreads();
    if (tid < NB) {
        float mm = fred[0][tid];
        #pragma unroll
        for (int j = 1; j < 8; ++j) mm = fminf(mm, fred[j][tid]);
        out[tid * NSHAPE + s] = sqrtf(fmaxf(mm, 1e-12f));
    }
}

extern "C" void kernel_launch(void* const* d_in, const int* in_sizes, int n_in,
                              void* d_out, int out_size, void* d_ws, size_t ws_size,
                              hipStream_t stream) {
    // inputs: times (L), path (B,L,C), lengths (NSHAPE), shapelets (NSHAPE,K,C)
    const float* path      = (const float*)d_in[1];
    const float* lengths   = (const float*)d_in[2];
    const float* shapelets = (const float*)d_in[3];
    float* out = (float*)d_out;

    float* wst     = (float*)d_ws;                                       // 4 MB
    float* partial = (float*)((char*)d_ws + (size_t)L_LEN * NB * CH * 4); // 256 KB

    transpose_kernel<<<L_LEN * NB * CH / 4 / 256, 256, 0, stream>>>(
        (const float4*)path, (float4*)wst);
    dim3 grid(NPBLK, NSHAPE);
    shapelet_min_kernel<<<grid, THREADS, 0, stream>>>(wst, lengths, shapelets, partial);
    shapelet_finalize_kernel<<<NSHAPE, 256, 0, stream>>>(partial, out);
}